// Round 1
// baseline (217.440 us; speedup 1.0000x reference)
//
#include <hip/hip_runtime.h>
#include <stdint.h>

typedef float f32x4 __attribute__((ext_vector_type(4)));
typedef __bf16 bf16x8 __attribute__((ext_vector_type(8)));
typedef unsigned short ushort8 __attribute__((ext_vector_type(8)));
typedef unsigned short u16;

#define DEVINL static __device__ __forceinline__

// fp32 -> bf16 round-to-nearest-even (bit-level, no API dependence)
DEVINL u16 f2bf(float f) {
  unsigned int u = __float_as_uint(f);
  return (u16)((u + 0x7fffu + ((u >> 16) & 1u)) >> 16);
}

// async global->LDS, 16B per lane. LDS dest must be wave-uniform base + lane*16.
DEVINL void gload16(const void* g, void* l) {
  __builtin_amdgcn_global_load_lds((__attribute__((address_space(1))) void*)g,
                                   (__attribute__((address_space(3))) void*)l, 16, 0, 0);
}

DEVINL f32x4 mfma16(bf16x8 a, bf16x8 b, f32x4 c) {
  return __builtin_amdgcn_mfma_f32_16x16x32_bf16(a, b, c, 0, 0, 0);
}

// ---------------- cast x (fp32) -> bf16, same layout ----------------
__global__ __launch_bounds__(256) void k_cast_bf16(const float* __restrict__ in,
                                                   u16* __restrict__ out) {
  const int i = blockIdx.x * 256 + threadIdx.x;  // 8 elems per thread
  const float4* p = (const float4*)in + (size_t)i * 2;
  float4 a = p[0], b = p[1];
  ushort8 o;
  o[0] = f2bf(a.x); o[1] = f2bf(a.y); o[2] = f2bf(a.z); o[3] = f2bf(a.w);
  o[4] = f2bf(b.x); o[5] = f2bf(b.y); o[6] = f2bf(b.z); o[7] = f2bf(b.w);
  *((ushort8*)out + i) = o;
}

// ---------------- transpose-cast: in [R][C] fp32 -> out [C][R] bf16 ----------------
__global__ __launch_bounds__(256) void k_tcast(const float* __restrict__ in,
                                               u16* __restrict__ out, int R, int C) {
  __shared__ float tile[32][33];
  const int tx = threadIdx.x & 31, ty = threadIdx.x >> 5;
  const int c0 = blockIdx.x * 32, r0 = blockIdx.y * 32;
#pragma unroll
  for (int k = 0; k < 4; ++k)
    tile[ty + k * 8][tx] = in[(size_t)(r0 + ty + k * 8) * C + (c0 + tx)];
  __syncthreads();
#pragma unroll
  for (int k = 0; k < 4; ++k)
    out[(size_t)(c0 + ty + k * 8) * R + (r0 + tx)] = f2bf(tile[tx][ty + k * 8]);
}

// ---------------- GEMM core: 128x128 tile, BK=64, 4 waves (2x2 of 64x64) ----------
// LDS tiles are [128 rows][64 bf16] linear, with 16B-granule XOR swizzle
// (g ^= row&7) applied on the *global source* during global_load_lds staging
// and on the ds_read side -> conflict-free ds_read_b128.
DEVINL void stage128x64(const u16* __restrict__ g, int ld, u16* lds, int t) {
#pragma unroll
  for (int i = 0; i < 4; ++i) {
    int ci = i * 256 + t;          // 1024 chunks of 16B
    int row = ci >> 3, gr = ci & 7;
    int gs = gr ^ (row & 7);       // pre-swizzled source granule
    gload16(g + (size_t)row * ld + gs * 8, lds + ci * 8);
  }
}

DEVINL void gemm_core(const u16* __restrict__ A, const u16* __restrict__ B, int Kdim,
                      u16* As, u16* Bs, int t, f32x4 acc[4][4]) {
  const int l = t & 63, lr = l & 15, lg = l >> 4;
  const int wr = t >> 7, wc = (t >> 6) & 1;
  for (int kt = 0; kt < Kdim; kt += 64) {
    __syncthreads();               // previous-iter LDS reads done
    stage128x64(A + kt, Kdim, As, t);
    stage128x64(B + kt, Kdim, Bs, t);
    __syncthreads();               // compiler drains vmcnt before barrier
#pragma unroll
    for (int ks = 0; ks < 2; ++ks) {
      bf16x8 af[4], bf[4];
#pragma unroll
      for (int mi = 0; mi < 4; ++mi) {
        int r = wr * 64 + mi * 16 + lr;
        int g = (ks * 4 + lg) ^ (r & 7);
        af[mi] = *(const bf16x8*)(As + r * 64 + g * 8);
      }
#pragma unroll
      for (int ni = 0; ni < 4; ++ni) {
        int r = wc * 64 + ni * 16 + lr;
        int g = (ks * 4 + lg) ^ (r & 7);
        bf[ni] = *(const bf16x8*)(Bs + r * 64 + g * 8);
      }
#pragma unroll
      for (int mi = 0; mi < 4; ++mi)
#pragma unroll
        for (int ni = 0; ni < 4; ++ni)
          acc[mi][ni] = mfma16(af[mi], bf[ni], acc[mi][ni]);
    }
  }
}

// ---------------- GEMM 1: qkv = xb @ W_attn + b, scatter to Q/K/V [BH][T][D] ------
__global__ __launch_bounds__(256) void k_gemm_qkv(const u16* __restrict__ xb,
                                                  const u16* __restrict__ WaT,
                                                  const float* __restrict__ b_attn,
                                                  u16* __restrict__ Qo,
                                                  u16* __restrict__ Ko,
                                                  u16* __restrict__ Vo) {
  __shared__ u16 As[128 * 64], Bs[128 * 64];
  const int t = threadIdx.x;
  const int m0 = blockIdx.y * 128, n0 = blockIdx.x * 128;
  f32x4 acc[4][4] = {};
  gemm_core(xb + (size_t)m0 * 1024, WaT + (size_t)n0 * 1024, 1024, As, Bs, t, acc);
  const int l = t & 63, lr = l & 15, lg = l >> 4;
  const int wr = t >> 7, wc = (t >> 6) & 1;
#pragma unroll
  for (int ni = 0; ni < 4; ++ni) {
    const int gcol = n0 + wc * 64 + ni * 16 + lr;
    const int part = gcol >> 10;               // 0=q 1=k 2=v
    const int h = (gcol & 1023) >> 6, d = gcol & 63;
    const float bias = b_attn[gcol];
    u16* dst = (part == 0) ? Qo : (part == 1) ? Ko : Vo;
#pragma unroll
    for (int mi = 0; mi < 4; ++mi)
#pragma unroll
      for (int r = 0; r < 4; ++r) {
        const int grow = m0 + wr * 64 + mi * 16 + lg * 4 + r;   // b*T + t
        const int bb = grow >> 11, tt = grow & 2047;
        dst[(size_t)((bb * 16 + h) * 2048 + tt) * 64 + d] = f2bf(acc[mi][ni][r] + bias);
      }
  }
}

// ---------------- GEMM 2: out = Y @ W_proj + b (fp32 out) ----------------
__global__ __launch_bounds__(256) void k_gemm_proj(const u16* __restrict__ Yb,
                                                   const u16* __restrict__ WpT,
                                                   const float* __restrict__ b_proj,
                                                   float* __restrict__ out) {
  __shared__ u16 As[128 * 64], Bs[128 * 64];
  const int t = threadIdx.x;
  const int m0 = blockIdx.y * 128, n0 = blockIdx.x * 128;
  f32x4 acc[4][4] = {};
  gemm_core(Yb + (size_t)m0 * 1024, WpT + (size_t)n0 * 1024, 1024, As, Bs, t, acc);
  const int l = t & 63, lr = l & 15, lg = l >> 4;
  const int wr = t >> 7, wc = (t >> 6) & 1;
#pragma unroll
  for (int ni = 0; ni < 4; ++ni) {
    const int gcol = n0 + wc * 64 + ni * 16 + lr;
    const float bias = b_proj[gcol];
#pragma unroll
    for (int mi = 0; mi < 4; ++mi)
#pragma unroll
      for (int r = 0; r < 4; ++r) {
        const int grow = m0 + wr * 64 + mi * 16 + lg * 4 + r;
        out[(size_t)grow * 1024 + gcol] = acc[mi][ni][r] + bias;
      }
  }
}

// ---------------- flash attention (causal), 4 waves x 16 q-rows, KV tile 64 -------
// LDS row stride 72 shorts (144B = 9 granules): consecutive rows shift bank-granule
// by 1 -> ds_read_b128 across 16 rows is 2-way (free). Qs reused as P buffer.
__global__ __launch_bounds__(256) void k_flash(const u16* __restrict__ Q,
                                               const u16* __restrict__ K,
                                               const u16* __restrict__ V,
                                               u16* __restrict__ Y) {
  __shared__ u16 Qs[64 * 72];   // becomes Ps after Q hoisted to registers
  __shared__ u16 Ks[64 * 72];
  __shared__ u16 Vts[64 * 72];  // V transposed: [d][key]
  const int t = threadIdx.x, l = t & 63, w = t >> 6, lr = l & 15, lg = l >> 4;
  const int qt = gridDim.x - 1 - blockIdx.x;   // long blocks launch first
  const int bh = blockIdx.y;
  const size_t base = (size_t)bh * (2048 * 64);

#pragma unroll
  for (int i = 0; i < 2; ++i) {
    int ci = i * 256 + t, row = ci >> 3, g = ci & 7;
    *(ushort8*)(Qs + row * 72 + g * 8) =
        *(const ushort8*)(Q + base + (size_t)(qt * 64 + row) * 64 + g * 8);
  }
  __syncthreads();
  // hoist this wave's Q fragments (constant over kv loop)
  bf16x8 qa0 = *(const bf16x8*)(Qs + (w * 16 + lr) * 72 + lg * 8);
  bf16x8 qa1 = *(const bf16x8*)(Qs + (w * 16 + lr) * 72 + 32 + lg * 8);

  f32x4 accO[4] = {};
  float m_old[4] = {-1e30f, -1e30f, -1e30f, -1e30f};
  float l_run[4] = {0.f, 0.f, 0.f, 0.f};
  u16* Ps = Qs;

  for (int kt = 0; kt <= qt; ++kt) {
    __syncthreads();   // previous-iter K/V reads done
    // stage K tile [64 keys][64 d]
#pragma unroll
    for (int i = 0; i < 2; ++i) {
      int ci = i * 256 + t, row = ci >> 3, g = ci & 7;
      *(ushort8*)(Ks + row * 72 + g * 8) =
          *(const ushort8*)(K + base + (size_t)(kt * 64 + row) * 64 + g * 8);
    }
    // stage V transposed: thread owns d=l, keys w*16..w*16+15
    {
      ushort8 w0, w1;
#pragma unroll
      for (int j = 0; j < 8; ++j)
        w0[j] = V[base + (size_t)(kt * 64 + w * 16 + j) * 64 + l];
#pragma unroll
      for (int j = 0; j < 8; ++j)
        w1[j] = V[base + (size_t)(kt * 64 + w * 16 + 8 + j) * 64 + l];
      *(ushort8*)(Vts + l * 72 + w * 16) = w0;
      *(ushort8*)(Vts + l * 72 + w * 16 + 8) = w1;
    }
    __syncthreads();

    // S = Q K^T (this wave: 16 q-rows x 64 keys)
    f32x4 sf[4] = {};
#pragma unroll
    for (int ni = 0; ni < 4; ++ni) {
      bf16x8 kb0 = *(const bf16x8*)(Ks + (ni * 16 + lr) * 72 + lg * 8);
      bf16x8 kb1 = *(const bf16x8*)(Ks + (ni * 16 + lr) * 72 + 32 + lg * 8);
      sf[ni] = mfma16(qa0, kb0, sf[ni]);
      sf[ni] = mfma16(qa1, kb1, sf[ni]);
    }
    // scale + causal mask
    float s[4][4];
    const int qrow0 = qt * 64 + w * 16 + lg * 4;
#pragma unroll
    for (int ni = 0; ni < 4; ++ni) {
      const int key = kt * 64 + ni * 16 + lr;
#pragma unroll
      for (int r = 0; r < 4; ++r) {
        float v2 = sf[ni][r] * 0.125f;
        if (kt == qt && key > qrow0 + r) v2 = -1e30f;
        s[ni][r] = v2;
      }
    }
    // online softmax (rows live in 16-lane groups)
    float mt[4];
#pragma unroll
    for (int r = 0; r < 4; ++r)
      mt[r] = fmaxf(fmaxf(s[0][r], s[1][r]), fmaxf(s[2][r], s[3][r]));
#pragma unroll
    for (int off = 8; off >= 1; off >>= 1)
#pragma unroll
      for (int r = 0; r < 4; ++r) mt[r] = fmaxf(mt[r], __shfl_xor(mt[r], off));
    float mn[4], al[4], rs[4];
#pragma unroll
    for (int r = 0; r < 4; ++r) {
      mn[r] = fmaxf(m_old[r], mt[r]);
      al[r] = __expf(m_old[r] - mn[r]);
      rs[r] = 0.f;
    }
#pragma unroll
    for (int ni = 0; ni < 4; ++ni)
#pragma unroll
      for (int r = 0; r < 4; ++r) {
        float p = __expf(s[ni][r] - mn[r]);
        rs[r] += p;
        Ps[(w * 16 + lg * 4 + r) * 72 + ni * 16 + lr] = f2bf(p);  // wave-private rows
      }
#pragma unroll
    for (int off = 8; off >= 1; off >>= 1)
#pragma unroll
      for (int r = 0; r < 4; ++r) rs[r] += __shfl_xor(rs[r], off);
#pragma unroll
    for (int r = 0; r < 4; ++r) {
      l_run[r] = l_run[r] * al[r] + rs[r];
      m_old[r] = mn[r];
    }
#pragma unroll
    for (int oi = 0; oi < 4; ++oi)
#pragma unroll
      for (int r = 0; r < 4; ++r) accO[oi][r] *= al[r];
    // O += P V   (A = P[16q x 32key], B = V[key][d] read from Vts[d][key])
#pragma unroll
    for (int ks = 0; ks < 2; ++ks) {
      bf16x8 pa = *(const bf16x8*)(Ps + (w * 16 + lr) * 72 + ks * 32 + lg * 8);
#pragma unroll
      for (int oi = 0; oi < 4; ++oi) {
        bf16x8 vb = *(const bf16x8*)(Vts + (oi * 16 + lr) * 72 + ks * 32 + lg * 8);
        accO[oi] = mfma16(pa, vb, accO[oi]);
      }
    }
  }
  // finalize: O /= l, write Y [B][T][C] bf16
  const int b = bh >> 4, h = bh & 15;
#pragma unroll
  for (int r = 0; r < 4; ++r) {
    const float inv = 1.0f / l_run[r];
    const int trow = qt * 64 + w * 16 + lg * 4 + r;
#pragma unroll
    for (int oi = 0; oi < 4; ++oi) {
      const int col = h * 64 + oi * 16 + lr;
      Y[(size_t)(b * 2048 + trow) * 1024 + col] = f2bf(accO[oi][r] * inv);
    }
  }
}

// ---------------- launch ----------------
extern "C" void kernel_launch(void* const* d_in, const int* in_sizes, int n_in,
                              void* d_out, int out_size, void* d_ws, size_t ws_size,
                              hipStream_t stream) {
  const float* x      = (const float*)d_in[0];
  const float* W_attn = (const float*)d_in[1];
  const float* b_attn = (const float*)d_in[2];
  const float* W_proj = (const float*)d_in[3];
  const float* b_proj = (const float*)d_in[4];
  float* out = (float*)d_out;

  char* ws = (char*)d_ws;              // 48 MB total
  u16* xb  = (u16*)(ws);               //  8 MB  x as bf16 [4096][1024]
  u16* WaT = (u16*)(ws + (8u  << 20)); //  6 MB  W_attn^T bf16 [3072][1024]
  u16* WpT = (u16*)(ws + (14u << 20)); //  2 MB  W_proj^T bf16 [1024][1024]
  u16* Qb  = (u16*)(ws + (16u << 20)); //  8 MB  [B*H][T][D]
  u16* Kb  = (u16*)(ws + (24u << 20)); //  8 MB
  u16* Vb  = (u16*)(ws + (32u << 20)); //  8 MB
  u16* Yb  = (u16*)(ws + (40u << 20)); //  8 MB  attn out bf16 [4096][1024]

  k_cast_bf16<<<dim3(2048), dim3(256), 0, stream>>>(x, xb);
  k_tcast<<<dim3(96, 32), dim3(256), 0, stream>>>(W_attn, WaT, 1024, 3072);
  k_tcast<<<dim3(32, 32), dim3(256), 0, stream>>>(W_proj, WpT, 1024, 1024);
  k_gemm_qkv<<<dim3(24, 32), dim3(256), 0, stream>>>(xb, WaT, b_attn, Qb, Kb, Vb);
  k_flash<<<dim3(32, 32), dim3(256), 0, stream>>>(Qb, Kb, Vb, Yb);
  k_gemm_proj<<<dim3(8, 32), dim3(256), 0, stream>>>(Yb, WpT, b_proj, out);
}

// Round 2
// 154.601 us; speedup vs baseline: 1.4065x; 1.4065x over previous
//
#include <hip/hip_runtime.h>
#include <stdint.h>

typedef float f32x4 __attribute__((ext_vector_type(4)));
typedef __bf16 bf16x8 __attribute__((ext_vector_type(8)));
typedef unsigned short ushort8 __attribute__((ext_vector_type(8)));
typedef unsigned short u16;

#define DEVINL static __device__ __forceinline__

// fp32 -> bf16 round-to-nearest-even (bit-level, no API dependence)
DEVINL u16 f2bf(float f) {
  unsigned int u = __float_as_uint(f);
  return (u16)((u + 0x7fffu + ((u >> 16) & 1u)) >> 16);
}

// async global->LDS, 16B per lane. LDS dest must be wave-uniform base + lane*16.
DEVINL void gload16(const void* g, void* l) {
  __builtin_amdgcn_global_load_lds((__attribute__((address_space(1))) void*)g,
                                   (__attribute__((address_space(3))) void*)l, 16, 0, 0);
}

DEVINL f32x4 mfma16(bf16x8 a, bf16x8 b, f32x4 c) {
  return __builtin_amdgcn_mfma_f32_16x16x32_bf16(a, b, c, 0, 0, 0);
}

// ---------------- cast x (fp32) -> bf16, same layout ----------------
__global__ __launch_bounds__(256) void k_cast_bf16(const float* __restrict__ in,
                                                   u16* __restrict__ out) {
  const int i = blockIdx.x * 256 + threadIdx.x;  // 8 elems per thread
  const float4* p = (const float4*)in + (size_t)i * 2;
  float4 a = p[0], b = p[1];
  ushort8 o;
  o[0] = f2bf(a.x); o[1] = f2bf(a.y); o[2] = f2bf(a.z); o[3] = f2bf(a.w);
  o[4] = f2bf(b.x); o[5] = f2bf(b.y); o[6] = f2bf(b.z); o[7] = f2bf(b.w);
  *((ushort8*)out + i) = o;
}

// ---------------- transpose-cast: in [R][C] fp32 -> out [C][R] bf16 ----------------
__global__ __launch_bounds__(256) void k_tcast(const float* __restrict__ in,
                                               u16* __restrict__ out, int R, int C) {
  __shared__ float tile[32][33];
  const int tx = threadIdx.x & 31, ty = threadIdx.x >> 5;
  const int c0 = blockIdx.x * 32, r0 = blockIdx.y * 32;
#pragma unroll
  for (int k = 0; k < 4; ++k)
    tile[ty + k * 8][tx] = in[(size_t)(r0 + ty + k * 8) * C + (c0 + tx)];
  __syncthreads();
#pragma unroll
  for (int k = 0; k < 4; ++k)
    out[(size_t)(c0 + ty + k * 8) * R + (r0 + tx)] = f2bf(tile[tx][ty + k * 8]);
}

// ---------------- V transpose: Vb [BH][T][64] -> Vt [BH][64][T] (bf16) ----------
__global__ __launch_bounds__(256) void k_vtrans(const u16* __restrict__ V,
                                                u16* __restrict__ Vt) {
  const int t = threadIdx.x;
  const size_t base = (size_t)blockIdx.y * 131072;  // 2048*64
  const int t0 = blockIdx.x * 64;
  const int d = t & 63, kg = t >> 6;  // this thread: column d, keys kg*16..kg*16+15
  ushort8 a, b;
#pragma unroll
  for (int j = 0; j < 8; ++j)
    a[j] = V[base + (size_t)(t0 + kg * 16 + j) * 64 + d];
#pragma unroll
  for (int j = 0; j < 8; ++j)
    b[j] = V[base + (size_t)(t0 + kg * 16 + 8 + j) * 64 + d];
  *(ushort8*)(Vt + base + (size_t)d * 2048 + t0 + kg * 16) = a;
  *(ushort8*)(Vt + base + (size_t)d * 2048 + t0 + kg * 16 + 8) = b;
}

// ---------------- GEMM core: 128x128 tile, BK=64, 4 waves (2x2 of 64x64) ----------
DEVINL void stage128x64(const u16* __restrict__ g, int ld, u16* lds, int t) {
#pragma unroll
  for (int i = 0; i < 4; ++i) {
    int ci = i * 256 + t;          // 1024 chunks of 16B
    int row = ci >> 3, gr = ci & 7;
    int gs = gr ^ (row & 7);       // pre-swizzled source granule
    gload16(g + (size_t)row * ld + gs * 8, lds + ci * 8);
  }
}

DEVINL void gemm_core(const u16* __restrict__ A, const u16* __restrict__ B, int Kdim,
                      u16* As, u16* Bs, int t, f32x4 acc[4][4]) {
  const int l = t & 63, lr = l & 15, lg = l >> 4;
  const int wr = t >> 7, wc = (t >> 6) & 1;
  for (int kt = 0; kt < Kdim; kt += 64) {
    __syncthreads();               // previous-iter LDS reads done
    stage128x64(A + kt, Kdim, As, t);
    stage128x64(B + kt, Kdim, Bs, t);
    __syncthreads();               // compiler drains vmcnt before barrier
#pragma unroll
    for (int ks = 0; ks < 2; ++ks) {
      bf16x8 af[4], bf[4];
#pragma unroll
      for (int mi = 0; mi < 4; ++mi) {
        int r = wr * 64 + mi * 16 + lr;
        int g = (ks * 4 + lg) ^ (r & 7);
        af[mi] = *(const bf16x8*)(As + r * 64 + g * 8);
      }
#pragma unroll
      for (int ni = 0; ni < 4; ++ni) {
        int r = wc * 64 + ni * 16 + lr;
        int g = (ks * 4 + lg) ^ (r & 7);
        bf[ni] = *(const bf16x8*)(Bs + r * 64 + g * 8);
      }
#pragma unroll
      for (int mi = 0; mi < 4; ++mi)
#pragma unroll
        for (int ni = 0; ni < 4; ++ni)
          acc[mi][ni] = mfma16(af[mi], bf[ni], acc[mi][ni]);
    }
  }
}

// ---------------- GEMM 1: qkv = xb @ W_attn + b, scatter to Q/K/V [BH][T][D] ------
__global__ __launch_bounds__(256) void k_gemm_qkv(const u16* __restrict__ xb,
                                                  const u16* __restrict__ WaT,
                                                  const float* __restrict__ b_attn,
                                                  u16* __restrict__ Qo,
                                                  u16* __restrict__ Ko,
                                                  u16* __restrict__ Vo) {
  __shared__ u16 As[128 * 64], Bs[128 * 64];
  const int t = threadIdx.x;
  const int m0 = blockIdx.y * 128, n0 = blockIdx.x * 128;
  f32x4 acc[4][4] = {};
  gemm_core(xb + (size_t)m0 * 1024, WaT + (size_t)n0 * 1024, 1024, As, Bs, t, acc);
  const int l = t & 63, lr = l & 15, lg = l >> 4;
  const int wr = t >> 7, wc = (t >> 6) & 1;
#pragma unroll
  for (int ni = 0; ni < 4; ++ni) {
    const int gcol = n0 + wc * 64 + ni * 16 + lr;
    const int part = gcol >> 10;               // 0=q 1=k 2=v
    const int h = (gcol & 1023) >> 6, d = gcol & 63;
    const float bias = b_attn[gcol];
    u16* dst = (part == 0) ? Qo : (part == 1) ? Ko : Vo;
#pragma unroll
    for (int mi = 0; mi < 4; ++mi)
#pragma unroll
      for (int r = 0; r < 4; ++r) {
        const int grow = m0 + wr * 64 + mi * 16 + lg * 4 + r;   // b*T + t
        const int bb = grow >> 11, tt = grow & 2047;
        dst[(size_t)((bb * 16 + h) * 2048 + tt) * 64 + d] = f2bf(acc[mi][ni][r] + bias);
      }
  }
}

// ---------------- GEMM 2: out = Y @ W_proj + b (fp32 out) ----------------
__global__ __launch_bounds__(256) void k_gemm_proj(const u16* __restrict__ Yb,
                                                   const u16* __restrict__ WpT,
                                                   const float* __restrict__ b_proj,
                                                   float* __restrict__ out) {
  __shared__ u16 As[128 * 64], Bs[128 * 64];
  const int t = threadIdx.x;
  const int m0 = blockIdx.y * 128, n0 = blockIdx.x * 128;
  f32x4 acc[4][4] = {};
  gemm_core(Yb + (size_t)m0 * 1024, WpT + (size_t)n0 * 1024, 1024, As, Bs, t, acc);
  const int l = t & 63, lr = l & 15, lg = l >> 4;
  const int wr = t >> 7, wc = (t >> 6) & 1;
#pragma unroll
  for (int ni = 0; ni < 4; ++ni) {
    const int gcol = n0 + wc * 64 + ni * 16 + lr;
    const float bias = b_proj[gcol];
#pragma unroll
    for (int mi = 0; mi < 4; ++mi)
#pragma unroll
      for (int r = 0; r < 4; ++r) {
        const int grow = m0 + wr * 64 + mi * 16 + lg * 4 + r;
        out[(size_t)grow * 1024 + gcol] = acc[mi][ni][r] + bias;
      }
  }
}

// ---------------- flash attention (causal), paired q-tiles, dbuf K/V ----------
// All LDS tiles: [64 rows][64 bf16] linear + 16B-granule XOR swizzle g^(row&7)
// (applied on the pre-swizzled global_load_lds source and on the ds_read side).
// Block bx handles q-tiles {bx, 31-bx}: exactly 33 KV iterations everywhere.
__global__ __launch_bounds__(256) void k_flash(const u16* __restrict__ Q,
                                               const u16* __restrict__ K,
                                               const u16* __restrict__ Vt,
                                               u16* __restrict__ Y) {
  __shared__ u16 Qs[64 * 64];      // reused as Ps (wave-private rows)
  __shared__ u16 Ks[2][64 * 64];
  __shared__ u16 Vs[2][64 * 64];   // V^T tiles: [d][key]
  const int t = threadIdx.x, l = t & 63, w = t >> 6, lr = l & 15, lg = l >> 4;
  const int bh = blockIdx.y;
  const size_t base = (size_t)bh * 131072;   // 2048*64 (same for K and Vt)
  const int b = bh >> 4, hh = bh & 15;
  u16* Ps = Qs;

  for (int half = 0; half < 2; ++half) {
    const int qt = half ? 31 - (int)blockIdx.x : (int)blockIdx.x;
    __syncthreads();   // LDS reuse across halves
    // stage Q tile + K/V tile 0
#pragma unroll
    for (int i = 0; i < 2; ++i) {
      int ci = i * 256 + t, row = ci >> 3, g = ci & 7, gs = g ^ (row & 7);
      gload16(Q + base + (size_t)(qt * 64 + row) * 64 + gs * 8, Qs + ci * 8);
      gload16(K + base + (size_t)row * 64 + gs * 8, Ks[0] + ci * 8);
      gload16(Vt + base + (size_t)row * 2048 + gs * 8, Vs[0] + ci * 8);
    }
    __syncthreads();
    // hoist this wave's Q fragments
    bf16x8 qa0, qa1;
    {
      const int r = w * 16 + lr, g0 = lg ^ (r & 7);
      qa0 = *(const bf16x8*)(Qs + r * 64 + g0 * 8);
      qa1 = *(const bf16x8*)(Qs + r * 64 + (g0 ^ 4) * 8);
    }
    f32x4 accO[4] = {};
    float m_old[4] = {-1e30f, -1e30f, -1e30f, -1e30f};
    float l_run[4] = {0.f, 0.f, 0.f, 0.f};

    for (int kt = 0; kt <= qt; ++kt) {
      const int cur = kt & 1;
      if (kt < qt) {   // prefetch next K/V tile (async; drained at loop-end barrier)
#pragma unroll
        for (int i = 0; i < 2; ++i) {
          int ci = i * 256 + t, row = ci >> 3, g = ci & 7, gs = g ^ (row & 7);
          gload16(K + base + (size_t)((kt + 1) * 64 + row) * 64 + gs * 8,
                  Ks[cur ^ 1] + ci * 8);
          gload16(Vt + base + (size_t)row * 2048 + (kt + 1) * 64 + gs * 8,
                  Vs[cur ^ 1] + ci * 8);
        }
      }
      // S = Q K^T (this wave: 16 q-rows x 64 keys)
      f32x4 sf[4] = {};
#pragma unroll
      for (int ni = 0; ni < 4; ++ni) {
        const int r2 = ni * 16 + lr, g0 = lg ^ (r2 & 7);
        bf16x8 kb0 = *(const bf16x8*)(Ks[cur] + r2 * 64 + g0 * 8);
        bf16x8 kb1 = *(const bf16x8*)(Ks[cur] + r2 * 64 + (g0 ^ 4) * 8);
        sf[ni] = mfma16(qa0, kb0, sf[ni]);
        sf[ni] = mfma16(qa1, kb1, sf[ni]);
      }
      // scale + causal mask
      float s[4][4];
      const int qrow0 = qt * 64 + w * 16 + lg * 4;
#pragma unroll
      for (int ni = 0; ni < 4; ++ni) {
        const int key = kt * 64 + ni * 16 + lr;
#pragma unroll
        for (int r = 0; r < 4; ++r) {
          float v2 = sf[ni][r] * 0.125f;
          if (kt == qt && key > qrow0 + r) v2 = -1e30f;
          s[ni][r] = v2;
        }
      }
      // online softmax (rows live in 16-lane groups)
      float mt[4];
#pragma unroll
      for (int r = 0; r < 4; ++r)
        mt[r] = fmaxf(fmaxf(s[0][r], s[1][r]), fmaxf(s[2][r], s[3][r]));
#pragma unroll
      for (int off = 8; off >= 1; off >>= 1)
#pragma unroll
        for (int r = 0; r < 4; ++r) mt[r] = fmaxf(mt[r], __shfl_xor(mt[r], off));
      float mn[4], al[4], rs[4];
#pragma unroll
      for (int r = 0; r < 4; ++r) {
        mn[r] = fmaxf(m_old[r], mt[r]);
        al[r] = __expf(m_old[r] - mn[r]);
        rs[r] = 0.f;
      }
#pragma unroll
      for (int ni = 0; ni < 4; ++ni)
#pragma unroll
        for (int r = 0; r < 4; ++r) {
          float p = __expf(s[ni][r] - mn[r]);
          rs[r] += p;
          const int prow = w * 16 + lg * 4 + r;
          const int cg = (ni * 2 + (lr >> 3)) ^ (prow & 7);   // swizzled granule
          Ps[prow * 64 + cg * 8 + (lr & 7)] = f2bf(p);
        }
#pragma unroll
      for (int off = 8; off >= 1; off >>= 1)
#pragma unroll
        for (int r = 0; r < 4; ++r) rs[r] += __shfl_xor(rs[r], off);
#pragma unroll
      for (int r = 0; r < 4; ++r) {
        l_run[r] = l_run[r] * al[r] + rs[r];
        m_old[r] = mn[r];
      }
#pragma unroll
      for (int oi = 0; oi < 4; ++oi)
#pragma unroll
        for (int r = 0; r < 4; ++r) accO[oi][r] *= al[r];
      // O += P V  (A = P rows, B = V^T rows; both swizzle-read)
#pragma unroll
      for (int ks = 0; ks < 2; ++ks) {
        const int rp = w * 16 + lr;
        bf16x8 pa = *(const bf16x8*)(Ps + rp * 64 + (((ks * 4 + lg) ^ (rp & 7)) * 8));
#pragma unroll
        for (int oi = 0; oi < 4; ++oi) {
          const int rv = oi * 16 + lr;
          bf16x8 vb =
              *(const bf16x8*)(Vs[cur] + rv * 64 + (((ks * 4 + lg) ^ (rv & 7)) * 8));
          accO[oi] = mfma16(pa, vb, accO[oi]);
        }
      }
      __syncthreads();   // all waves done with [cur]; prefetched loads drained
    }
    // finalize: O /= l, write Y [B][T][C] bf16
#pragma unroll
    for (int r = 0; r < 4; ++r) {
      const float inv = 1.0f / l_run[r];
      const int trow = qt * 64 + w * 16 + lg * 4 + r;
#pragma unroll
      for (int oi = 0; oi < 4; ++oi) {
        const int col = hh * 64 + oi * 16 + lr;
        Y[(size_t)(b * 2048 + trow) * 1024 + col] = f2bf(accO[oi][r] * inv);
      }
    }
  }
}

// ---------------- launch ----------------
extern "C" void kernel_launch(void* const* d_in, const int* in_sizes, int n_in,
                              void* d_out, int out_size, void* d_ws, size_t ws_size,
                              hipStream_t stream) {
  const float* x      = (const float*)d_in[0];
  const float* W_attn = (const float*)d_in[1];
  const float* b_attn = (const float*)d_in[2];
  const float* W_proj = (const float*)d_in[3];
  const float* b_proj = (const float*)d_in[4];
  float* out = (float*)d_out;

  char* ws = (char*)d_ws;              // 48 MB total
  u16* xb  = (u16*)(ws);               //  8 MB  x as bf16 [4096][1024]; later Vt
  u16* WaT = (u16*)(ws + (8u  << 20)); //  6 MB  W_attn^T bf16 [3072][1024]
  u16* WpT = (u16*)(ws + (14u << 20)); //  2 MB  W_proj^T bf16 [1024][1024]
  u16* Qb  = (u16*)(ws + (16u << 20)); //  8 MB  [B*H][T][D]
  u16* Kb  = (u16*)(ws + (24u << 20)); //  8 MB
  u16* Vb  = (u16*)(ws + (32u << 20)); //  8 MB
  u16* Yb  = (u16*)(ws + (40u << 20)); //  8 MB  attn out bf16 [4096][1024]
  u16* Vtb = xb;                       //  reuse: xb dead after k_gemm_qkv

  k_cast_bf16<<<dim3(2048), dim3(256), 0, stream>>>(x, xb);
  k_tcast<<<dim3(96, 32), dim3(256), 0, stream>>>(W_attn, WaT, 1024, 3072);
  k_tcast<<<dim3(32, 32), dim3(256), 0, stream>>>(W_proj, WpT, 1024, 1024);
  k_gemm_qkv<<<dim3(24, 32), dim3(256), 0, stream>>>(xb, WaT, b_attn, Qb, Kb, Vb);
  k_vtrans<<<dim3(32, 32), dim3(256), 0, stream>>>(Vb, Vtb);
  k_flash<<<dim3(16, 32), dim3(256), 0, stream>>>(Qb, Kb, Vtb, Yb);
  k_gemm_proj<<<dim3(8, 32), dim3(256), 0, stream>>>(Yb, WpT, b_proj, out);
}